// Round 1
// baseline (285.401 us; speedup 1.0000x reference)
//
#include <hip/hip_runtime.h>
#include <stdint.h>

#define IN_F   11008
#define OUT_F  4096
#define TOPK_K 5504
#define NCACHE 64
#define MASK_WORDS 344   // 11008 / 32
#define NCHUNK 11        // ceil(11008 / 1024)

// ws layout (bytes):
//   [0    , 1376) : topk mask bits (344 u32)
//   [1408 , 1412) : packed score u32, atomicMax of (inter<<6)|(63-row)
//   [1536 , 1536+44032) : counts (int per feature, multiplicity of best cached row)

__device__ __forceinline__ unsigned absbits(float v) {
    return __float_as_uint(v) & 0x7fffffffu;
}

// ---------------------------------------------------------------------------
// K0: exact radix-select of the 5504-th largest |x| (uint-encoded key), build
// the top-k mask with index-ordered tie-breaking (matches jax.lax.top_k).
// Latency-minimal single-block version: keys register-resident (loaded once),
// wave-0 shuffle suffix-scan instead of serial tid0 scans, ballot-based mask
// stores (each wave-chunk owns exactly 2 mask words -> no atomics, no 33-sync
// chunk loop). 1 block x 1024 threads.
// ---------------------------------------------------------------------------
__global__ __launch_bounds__(1024) void k_select(const float* __restrict__ x,
                                                 unsigned* __restrict__ maskbits_g,
                                                 unsigned* __restrict__ score_g,
                                                 int* __restrict__ counts_g) {
    __shared__ unsigned hist[16][256];   // per-wave private hists
    __shared__ unsigned csum[256];       // merged per-bucket counts
    __shared__ unsigned sh_T, sh_rem, sh_totEq;
    __shared__ unsigned waveEq[NCHUNK][16];
    __shared__ unsigned waveEqPre[NCHUNK][16];

    const int tid  = threadIdx.x;
    const int wv   = tid >> 6;
    const int lane = tid & 63;
    const int nk   = (tid < IN_F - 10 * 1024) ? NCHUNK : NCHUNK - 1;  // tid<768 -> 11 keys

    // single pass over x: keys live in registers for the whole kernel
    unsigned key[NCHUNK];
#pragma unroll
    for (int c = 0; c < NCHUNK; ++c) {
        key[c] = 0u;
        if (c < nk) key[c] = absbits(x[c * 1024 + tid]);
    }

    // zero aux outputs early (consumed only by later kernels)
    for (int i = tid; i < IN_F; i += 1024) counts_g[i] = 0;
    if (tid == 0) *score_g = 0;

    unsigned prefix = 0, maskHi = 0, remaining = TOPK_K;

    for (int pass = 3; pass >= 0; --pass) {
        const int sh = pass * 8;
        for (int b = tid; b < 16 * 256; b += 1024) ((unsigned*)hist)[b] = 0;
        __syncthreads();
#pragma unroll
        for (int c = 0; c < NCHUNK; ++c) {
            if (c < nk && (key[c] & maskHi) == prefix)
                atomicAdd(&hist[wv][(key[c] >> sh) & 255], 1u);
        }
        __syncthreads();
        if (tid < 256) {            // merge 16 hists, conflict-free (consecutive buckets)
            unsigned s = 0;
#pragma unroll
            for (int w = 0; w < 16; ++w) s += hist[w][tid];
            csum[tid] = s;
        }
        __syncthreads();
        if (wv == 0) {
            // lane l owns buckets [4l, 4l+4); inclusive suffix-scan across lanes
            unsigned c0 = csum[4 * lane + 0], c1 = csum[4 * lane + 1];
            unsigned c2 = csum[4 * lane + 2], c3 = csum[4 * lane + 3];
            unsigned S = c0 + c1 + c2 + c3;
#pragma unroll
            for (int off = 1; off < 64; off <<= 1) {
                unsigned v = __shfl_down(S, off, 64);
                if (lane + off < 64) S += v;
            }
            unsigned Sn = __shfl_down(S, 1, 64);
            if (lane == 63) Sn = 0;
            // per-bucket suffix sums within the lane's group
            unsigned t3 = Sn + c3;
            unsigned t2 = t3 + c2;
            unsigned t1 = t2 + c1;
            unsigned t0 = t1 + c0;
            unsigned rem = remaining;
            // unique crossing: suf(b) >= rem && suf(b+1) < rem
            if (t3 >= rem && Sn < rem) { sh_T = prefix | ((unsigned)(4 * lane + 3) << sh); sh_rem = rem - Sn; }
            if (t2 >= rem && t3 < rem) { sh_T = prefix | ((unsigned)(4 * lane + 2) << sh); sh_rem = rem - t3; }
            if (t1 >= rem && t2 < rem) { sh_T = prefix | ((unsigned)(4 * lane + 1) << sh); sh_rem = rem - t2; }
            if (t0 >= rem && t1 < rem) { sh_T = prefix | ((unsigned)(4 * lane + 0) << sh); sh_rem = rem - t1; }
        }
        __syncthreads();
        prefix = sh_T;
        maskHi |= 0xffu << sh;
        remaining = sh_rem;
    }

    const unsigned T = prefix;         // exact key of the k-th largest
    const unsigned eqTake = remaining; // #(key==T) to take, ascending index

    unsigned gtm = 0, eqm = 0;
#pragma unroll
    for (int c = 0; c < NCHUNK; ++c) {
        if (c < nk) {
            if (key[c] > T)       gtm |= 1u << c;
            else if (key[c] == T) eqm |= 1u << c;
        }
    }
#pragma unroll
    for (int c = 0; c < NCHUNK; ++c) {
        unsigned long long bal = __ballot((eqm >> c) & 1u);
        if (lane == 0) waveEq[c][wv] = (unsigned)__popcll(bal);
    }
    __syncthreads();
    if (tid < 64) {
        unsigned s = 0;
        for (int p = lane; p < NCHUNK * 16; p += 64) s += waveEq[p >> 4][p & 15];
#pragma unroll
        for (int off = 32; off > 0; off >>= 1) s += __shfl_down(s, off, 64);
        if (lane == 0) sh_totEq = s;
    }
    __syncthreads();
    const bool fast = (sh_totEq == eqTake);   // all ties taken (typical: 1 == 1)
    if (!fast) {
        if (tid == 0) {   // rare path: exact index-ordered ranking of ties
            unsigned run = 0;
            for (int c = 0; c < NCHUNK; ++c)
                for (int w = 0; w < 16; ++w) { waveEqPre[c][w] = run; run += waveEq[c][w]; }
        }
        __syncthreads();
    }
#pragma unroll
    for (int c = 0; c < NCHUNK; ++c) {
        bool eq = (eqm >> c) & 1u;
        bool take;
        if (fast) {
            take = (((gtm >> c) & 1u) != 0u) || eq;
        } else {
            unsigned long long balEq = __ballot(eq);
            unsigned rank = waveEqPre[c][wv] + (unsigned)__popcll(balEq & ((1ull << lane) - 1ull));
            take = (((gtm >> c) & 1u) != 0u) || (eq && rank < eqTake);
        }
        unsigned long long balT = __ballot(take);
        int w0 = c * 32 + wv * 2;            // this wave-chunk owns words w0, w0+1
        if (w0 < MASK_WORDS && lane == 0) {
            maskbits_g[w0]     = (unsigned)balT;
            maskbits_g[w0 + 1] = (unsigned)(balT >> 32);
        }
    }
}

// ---------------------------------------------------------------------------
// K1: recall per cached row via bitmask intersection (dedupes duplicates),
// argmax with lowest-row tie-break via packed atomicMax. 64 blocks x 256.
// ---------------------------------------------------------------------------
__global__ __launch_bounds__(256) void k_recall(const int* __restrict__ cached,
                                                const unsigned* __restrict__ maskbits_g,
                                                unsigned* __restrict__ score_g) {
    __shared__ unsigned rowbits[MASK_WORDS];
    __shared__ unsigned wsum[4];
    const int r = blockIdx.x;
    const int tid = threadIdx.x;
    for (int w = tid; w < MASK_WORDS; w += 256) rowbits[w] = 0;
    __syncthreads();
    const int4* ci4 = (const int4*)(cached + (size_t)r * TOPK_K);
    for (int t = tid; t < TOPK_K / 4; t += 256) {
        int4 v = ci4[t];
        atomicOr(&rowbits[v.x >> 5], 1u << (v.x & 31));
        atomicOr(&rowbits[v.y >> 5], 1u << (v.y & 31));
        atomicOr(&rowbits[v.z >> 5], 1u << (v.z & 31));
        atomicOr(&rowbits[v.w >> 5], 1u << (v.w & 31));
    }
    __syncthreads();
    unsigned cnt = 0;
    for (int w = tid; w < MASK_WORDS; w += 256) cnt += __popc(rowbits[w] & maskbits_g[w]);
    for (int off = 32; off > 0; off >>= 1) cnt += __shfl_down(cnt, off, 64);
    if ((tid & 63) == 0) wsum[tid >> 6] = cnt;
    __syncthreads();
    if (tid == 0) {
        unsigned tot = wsum[0] + wsum[1] + wsum[2] + wsum[3];
        atomicMax(score_g, (tot << 6) | (unsigned)(63 - r));
    }
}

// ---------------------------------------------------------------------------
// K2: multiplicity histogram of the best cached row (used only if recall>=0.9,
// computed unconditionally). 22 blocks x 256.
// ---------------------------------------------------------------------------
__global__ __launch_bounds__(256) void k_counts(const int* __restrict__ cached,
                                                const unsigned* __restrict__ score_g,
                                                int* __restrict__ counts_g) {
    unsigned score = *score_g;
    int best = 63 - (int)(score & 63u);
    int t = blockIdx.x * 256 + threadIdx.x;
    if (t < TOPK_K) atomicAdd(&counts_g[cached[best * TOPK_K + t]], 1);
}

// ---------------------------------------------------------------------------
// K3: dense GEMV out = W * (coef .* x) + bias. coef = mask (topk path) or
// multiplicity counts (cached path) — exactly reproduces duplicate columns.
// 512 blocks x 256 threads; xc staged in 44KB LDS; 1 wave per 2 output rows.
// UNCHANGED from verified baseline (clean attribution of the select rewrite).
// ---------------------------------------------------------------------------
#define ROWS_PER_BLOCK 8
__global__ __launch_bounds__(256) void k_gemv(const float* __restrict__ x,
                                              const float* __restrict__ W,
                                              const float* __restrict__ bias,
                                              const unsigned* __restrict__ maskbits_g,
                                              const unsigned* __restrict__ score_g,
                                              const int* __restrict__ counts_g,
                                              float* __restrict__ out) {
    __shared__ __align__(16) float xs[IN_F];
    const int tid = threadIdx.x;

    unsigned score = *score_g;
    unsigned inter = score >> 6;
    bool useCache = ((float)inter / (float)TOPK_K) >= 0.9f;

    const float4* x4 = (const float4*)x;
    for (int j = tid; j < IN_F / 4; j += 256) {
        float4 xv = x4[j];
        int base = j * 4;
        float c0, c1, c2, c3;
        if (useCache) {
            c0 = (float)counts_g[base + 0];
            c1 = (float)counts_g[base + 1];
            c2 = (float)counts_g[base + 2];
            c3 = (float)counts_g[base + 3];
        } else {
            unsigned wbits = maskbits_g[base >> 5];  // 4 consecutive bits share a word
            int sh = base & 31;
            c0 = (float)((wbits >> (sh + 0)) & 1u);
            c1 = (float)((wbits >> (sh + 1)) & 1u);
            c2 = (float)((wbits >> (sh + 2)) & 1u);
            c3 = (float)((wbits >> (sh + 3)) & 1u);
        }
        xs[base + 0] = xv.x * c0;
        xs[base + 1] = xv.y * c1;
        xs[base + 2] = xv.z * c2;
        xs[base + 3] = xv.w * c3;
    }
    __syncthreads();

    const int wv   = tid >> 6;
    const int lane = tid & 63;
    const int row0 = blockIdx.x * ROWS_PER_BLOCK + wv * 2;
    const int row1 = row0 + 1;
    const float4* w0p = (const float4*)(W + (size_t)row0 * IN_F);
    const float4* w1p = (const float4*)(W + (size_t)row1 * IN_F);
    const float4* xs4 = (const float4*)xs;

    float acc0 = 0.f, acc1 = 0.f;
#pragma unroll 4
    for (int j = lane; j < IN_F / 4; j += 64) {   // exactly 43 iters/lane
        float4 xv = xs4[j];
        float4 a  = w0p[j];
        float4 b  = w1p[j];
        acc0 += xv.x * a.x + xv.y * a.y + xv.z * a.z + xv.w * a.w;
        acc1 += xv.x * b.x + xv.y * b.y + xv.z * b.z + xv.w * b.w;
    }
    for (int off = 32; off > 0; off >>= 1) {
        acc0 += __shfl_down(acc0, off, 64);
        acc1 += __shfl_down(acc1, off, 64);
    }
    if (lane == 0) {
        out[row0] = acc0 + bias[row0];
        out[row1] = acc1 + bias[row1];
    }
}

extern "C" void kernel_launch(void* const* d_in, const int* in_sizes, int n_in,
                              void* d_out, int out_size, void* d_ws, size_t ws_size,
                              hipStream_t stream) {
    const float* x      = (const float*)d_in[0];
    const float* W      = (const float*)d_in[1];
    const float* bias   = (const float*)d_in[2];
    const int*   cached = (const int*)d_in[3];
    float* out = (float*)d_out;

    char* ws = (char*)d_ws;
    unsigned* maskbits = (unsigned*)(ws + 0);
    unsigned* score    = (unsigned*)(ws + 1408);
    int*      counts   = (int*)(ws + 1536);

    k_select<<<1, 1024, 0, stream>>>(x, maskbits, score, counts);
    k_recall<<<NCACHE, 256, 0, stream>>>(cached, maskbits, score);
    k_counts<<<(TOPK_K + 255) / 256, 256, 0, stream>>>(cached, score, counts);
    k_gemv<<<OUT_F / ROWS_PER_BLOCK, 256, 0, stream>>>(x, W, bias, maskbits, score, counts, out);
}

// Round 2
// 280.112 us; speedup vs baseline: 1.0189x; 1.0189x over previous
//
#include <hip/hip_runtime.h>
#include <stdint.h>

#define IN_F   11008
#define OUT_F  4096
#define TOPK_K 5504
#define NCACHE 64
#define MASK_WORDS 344   // 11008 / 32
#define NCHUNK 11        // ceil(11008 / 1024)

// ws layout (bytes):
//   [0    , 1376) : topk mask bits (344 u32)
//   [1408 , 1412) : packed score u32, atomicMax of (inter<<6)|(63-row)

__device__ __forceinline__ unsigned absbits(float v) {
    return __float_as_uint(v) & 0x7fffffffu;
}

// ---------------------------------------------------------------------------
// K0: exact radix-select of the 5504-th largest |x| (uint-encoded key), build
// the top-k mask with index-ordered tie-breaking (matches jax.lax.top_k).
// Keys register-resident (loaded once), wave-0 shuffle suffix-scan, ballot
// mask stores (each wave-chunk owns exactly 2 mask words). 1 block x 1024.
// (verified last round — unchanged except counts-zeroing removed)
// ---------------------------------------------------------------------------
__global__ __launch_bounds__(1024) void k_select(const float* __restrict__ x,
                                                 unsigned* __restrict__ maskbits_g,
                                                 unsigned* __restrict__ score_g) {
    __shared__ unsigned hist[16][256];   // per-wave private hists
    __shared__ unsigned csum[256];       // merged per-bucket counts
    __shared__ unsigned sh_T, sh_rem, sh_totEq;
    __shared__ unsigned waveEq[NCHUNK][16];
    __shared__ unsigned waveEqPre[NCHUNK][16];

    const int tid  = threadIdx.x;
    const int wv   = tid >> 6;
    const int lane = tid & 63;
    const int nk   = (tid < IN_F - 10 * 1024) ? NCHUNK : NCHUNK - 1;  // tid<768 -> 11 keys

    // single pass over x: keys live in registers for the whole kernel
    unsigned key[NCHUNK];
#pragma unroll
    for (int c = 0; c < NCHUNK; ++c) {
        key[c] = 0u;
        if (c < nk) key[c] = absbits(x[c * 1024 + tid]);
    }

    if (tid == 0) *score_g = 0;

    unsigned prefix = 0, maskHi = 0, remaining = TOPK_K;

    for (int pass = 3; pass >= 0; --pass) {
        const int sh = pass * 8;
        for (int b = tid; b < 16 * 256; b += 1024) ((unsigned*)hist)[b] = 0;
        __syncthreads();
#pragma unroll
        for (int c = 0; c < NCHUNK; ++c) {
            if (c < nk && (key[c] & maskHi) == prefix)
                atomicAdd(&hist[wv][(key[c] >> sh) & 255], 1u);
        }
        __syncthreads();
        if (tid < 256) {            // merge 16 hists, conflict-free (consecutive buckets)
            unsigned s = 0;
#pragma unroll
            for (int w = 0; w < 16; ++w) s += hist[w][tid];
            csum[tid] = s;
        }
        __syncthreads();
        if (wv == 0) {
            // lane l owns buckets [4l, 4l+4); inclusive suffix-scan across lanes
            unsigned c0 = csum[4 * lane + 0], c1 = csum[4 * lane + 1];
            unsigned c2 = csum[4 * lane + 2], c3 = csum[4 * lane + 3];
            unsigned S = c0 + c1 + c2 + c3;
#pragma unroll
            for (int off = 1; off < 64; off <<= 1) {
                unsigned v = __shfl_down(S, off, 64);
                if (lane + off < 64) S += v;
            }
            unsigned Sn = __shfl_down(S, 1, 64);
            if (lane == 63) Sn = 0;
            // per-bucket suffix sums within the lane's group
            unsigned t3 = Sn + c3;
            unsigned t2 = t3 + c2;
            unsigned t1 = t2 + c1;
            unsigned t0 = t1 + c0;
            unsigned rem = remaining;
            // unique crossing: suf(b) >= rem && suf(b+1) < rem
            if (t3 >= rem && Sn < rem) { sh_T = prefix | ((unsigned)(4 * lane + 3) << sh); sh_rem = rem - Sn; }
            if (t2 >= rem && t3 < rem) { sh_T = prefix | ((unsigned)(4 * lane + 2) << sh); sh_rem = rem - t3; }
            if (t1 >= rem && t2 < rem) { sh_T = prefix | ((unsigned)(4 * lane + 1) << sh); sh_rem = rem - t2; }
            if (t0 >= rem && t1 < rem) { sh_T = prefix | ((unsigned)(4 * lane + 0) << sh); sh_rem = rem - t1; }
        }
        __syncthreads();
        prefix = sh_T;
        maskHi |= 0xffu << sh;
        remaining = sh_rem;
    }

    const unsigned T = prefix;         // exact key of the k-th largest
    const unsigned eqTake = remaining; // #(key==T) to take, ascending index

    unsigned gtm = 0, eqm = 0;
#pragma unroll
    for (int c = 0; c < NCHUNK; ++c) {
        if (c < nk) {
            if (key[c] > T)       gtm |= 1u << c;
            else if (key[c] == T) eqm |= 1u << c;
        }
    }
#pragma unroll
    for (int c = 0; c < NCHUNK; ++c) {
        unsigned long long bal = __ballot((eqm >> c) & 1u);
        if (lane == 0) waveEq[c][wv] = (unsigned)__popcll(bal);
    }
    __syncthreads();
    if (tid < 64) {
        unsigned s = 0;
        for (int p = lane; p < NCHUNK * 16; p += 64) s += waveEq[p >> 4][p & 15];
#pragma unroll
        for (int off = 32; off > 0; off >>= 1) s += __shfl_down(s, off, 64);
        if (lane == 0) sh_totEq = s;
    }
    __syncthreads();
    const bool fast = (sh_totEq == eqTake);   // all ties taken (typical: 1 == 1)
    if (!fast) {
        if (tid == 0) {   // rare path: exact index-ordered ranking of ties
            unsigned run = 0;
            for (int c = 0; c < NCHUNK; ++c)
                for (int w = 0; w < 16; ++w) { waveEqPre[c][w] = run; run += waveEq[c][w]; }
        }
        __syncthreads();
    }
#pragma unroll
    for (int c = 0; c < NCHUNK; ++c) {
        bool eq = (eqm >> c) & 1u;
        bool take;
        if (fast) {
            take = (((gtm >> c) & 1u) != 0u) || eq;
        } else {
            unsigned long long balEq = __ballot(eq);
            unsigned rank = waveEqPre[c][wv] + (unsigned)__popcll(balEq & ((1ull << lane) - 1ull));
            take = (((gtm >> c) & 1u) != 0u) || (eq && rank < eqTake);
        }
        unsigned long long balT = __ballot(take);
        int w0 = c * 32 + wv * 2;            // this wave-chunk owns words w0, w0+1
        if (w0 < MASK_WORDS && lane == 0) {
            maskbits_g[w0]     = (unsigned)balT;
            maskbits_g[w0 + 1] = (unsigned)(balT >> 32);
        }
    }
}

// ---------------------------------------------------------------------------
// K1: recall per cached row via bitmask intersection (dedupes duplicates),
// argmax with lowest-row tie-break via packed atomicMax. 64 blocks x 256.
// ---------------------------------------------------------------------------
__global__ __launch_bounds__(256) void k_recall(const int* __restrict__ cached,
                                                const unsigned* __restrict__ maskbits_g,
                                                unsigned* __restrict__ score_g) {
    __shared__ unsigned rowbits[MASK_WORDS];
    __shared__ unsigned wsum[4];
    const int r = blockIdx.x;
    const int tid = threadIdx.x;
    for (int w = tid; w < MASK_WORDS; w += 256) rowbits[w] = 0;
    __syncthreads();
    const int4* ci4 = (const int4*)(cached + (size_t)r * TOPK_K);
    for (int t = tid; t < TOPK_K / 4; t += 256) {
        int4 v = ci4[t];
        atomicOr(&rowbits[v.x >> 5], 1u << (v.x & 31));
        atomicOr(&rowbits[v.y >> 5], 1u << (v.y & 31));
        atomicOr(&rowbits[v.z >> 5], 1u << (v.z & 31));
        atomicOr(&rowbits[v.w >> 5], 1u << (v.w & 31));
    }
    __syncthreads();
    unsigned cnt = 0;
    for (int w = tid; w < MASK_WORDS; w += 256) cnt += __popc(rowbits[w] & maskbits_g[w]);
    for (int off = 32; off > 0; off >>= 1) cnt += __shfl_down(cnt, off, 64);
    if ((tid & 63) == 0) wsum[tid >> 6] = cnt;
    __syncthreads();
    if (tid == 0) {
        unsigned tot = wsum[0] + wsum[1] + wsum[2] + wsum[3];
        atomicMax(score_g, (tot << 6) | (unsigned)(63 - r));
    }
}

// ---------------------------------------------------------------------------
// K2: dense GEMV out = W * (coef .* x) + bias. coef = mask (topk path) or
// duplicate-multiplicity of the best cached row (cached path, reconstructed
// in-block via LDS float atomics — no counts array / no extra kernel).
// 256 blocks x 512 threads; x staged in 44KB LDS; 1 wave per 2 rows,
// 16 rows/block, exactly 1 block per CU.
// ---------------------------------------------------------------------------
#define ROWS_PER_BLOCK 16
#define GEMV_THREADS   512
__global__ __launch_bounds__(GEMV_THREADS) void k_gemv(const float* __restrict__ x,
                                                       const float* __restrict__ W,
                                                       const float* __restrict__ bias,
                                                       const unsigned* __restrict__ maskbits_g,
                                                       const unsigned* __restrict__ score_g,
                                                       const int* __restrict__ cached,
                                                       float* __restrict__ out) {
    __shared__ __align__(16) float xs[IN_F];
    const int tid = threadIdx.x;

    unsigned score = *score_g;
    unsigned inter = score >> 6;
    bool useCache = ((float)inter / (float)TOPK_K) >= 0.9f;

    if (useCache) {
        // coef[i] = multiplicity of i in best row; xs[i] = coef[i]*x[i]
        int best = 63 - (int)(score & 63u);
        for (int i = tid; i < IN_F; i += GEMV_THREADS) xs[i] = 0.f;
        __syncthreads();
        const int* ci = cached + (size_t)best * TOPK_K;
        for (int t = tid; t < TOPK_K; t += GEMV_THREADS) {
            int idx = ci[t];
            atomicAdd(&xs[idx], x[idx]);   // duplicates accumulate -> count*x
        }
    } else {
        const float4* x4 = (const float4*)x;
        for (int j = tid; j < IN_F / 4; j += GEMV_THREADS) {
            float4 xv = x4[j];
            int base = j * 4;
            unsigned wbits = maskbits_g[base >> 5];  // 4 consecutive bits share a word
            int sh = base & 31;
            xs[base + 0] = xv.x * (float)((wbits >> (sh + 0)) & 1u);
            xs[base + 1] = xv.y * (float)((wbits >> (sh + 1)) & 1u);
            xs[base + 2] = xv.z * (float)((wbits >> (sh + 2)) & 1u);
            xs[base + 3] = xv.w * (float)((wbits >> (sh + 3)) & 1u);
        }
    }
    __syncthreads();

    const int wv   = tid >> 6;
    const int lane = tid & 63;
    const int row0 = blockIdx.x * ROWS_PER_BLOCK + wv * 2;
    const int row1 = row0 + 1;
    const float4* w0p = (const float4*)(W + (size_t)row0 * IN_F);
    const float4* w1p = (const float4*)(W + (size_t)row1 * IN_F);
    const float4* xs4 = (const float4*)xs;

    float acc0 = 0.f, acc1 = 0.f;
#pragma unroll 4
    for (int j = lane; j < IN_F / 4; j += 64) {   // exactly 43 iters/lane
        float4 xv = xs4[j];
        float4 a  = w0p[j];
        float4 b  = w1p[j];
        acc0 += xv.x * a.x + xv.y * a.y + xv.z * a.z + xv.w * a.w;
        acc1 += xv.x * b.x + xv.y * b.y + xv.z * b.z + xv.w * b.w;
    }
    for (int off = 32; off > 0; off >>= 1) {
        acc0 += __shfl_down(acc0, off, 64);
        acc1 += __shfl_down(acc1, off, 64);
    }
    if (lane == 0) {
        out[row0] = acc0 + bias[row0];
        out[row1] = acc1 + bias[row1];
    }
}

extern "C" void kernel_launch(void* const* d_in, const int* in_sizes, int n_in,
                              void* d_out, int out_size, void* d_ws, size_t ws_size,
                              hipStream_t stream) {
    const float* x      = (const float*)d_in[0];
    const float* W      = (const float*)d_in[1];
    const float* bias   = (const float*)d_in[2];
    const int*   cached = (const int*)d_in[3];
    float* out = (float*)d_out;

    char* ws = (char*)d_ws;
    unsigned* maskbits = (unsigned*)(ws + 0);
    unsigned* score    = (unsigned*)(ws + 1408);

    k_select<<<1, 1024, 0, stream>>>(x, maskbits, score);
    k_recall<<<NCACHE, 256, 0, stream>>>(cached, maskbits, score);
    k_gemv<<<OUT_F / ROWS_PER_BLOCK, GEMV_THREADS, 0, stream>>>(x, W, bias, maskbits, score, cached, out);
}